// Round 1
// baseline (2545.558 us; speedup 1.0000x reference)
//
#include <hip/hip_runtime.h>
#include <cstddef>
#include <cstdint>

#define CH 128   // IN_CH == HID_CH == 128
#define TM 128   // GEMM rows per block
#define TK 16    // GEMM K-chunk

// ============================ CSR build (counting sort by dst) ============================

__global__ void k_hist(const int* __restrict__ dst, int* __restrict__ deg, int E) {
  int e = blockIdx.x * 256 + threadIdx.x;
  if (e < E) atomicAdd(&deg[dst[e]], 1);
}

// per-chunk (1024 elems) exclusive scan; chunk totals to bsums
__global__ void k_scan1(const int* __restrict__ deg, int* __restrict__ rowptr,
                        int* __restrict__ bsums, int n) {
  __shared__ int sh[256];
  int tid = threadIdx.x;
  int base = blockIdx.x * 1024 + tid * 4;
  int v0 = (base + 0 < n) ? deg[base + 0] : 0;
  int v1 = (base + 1 < n) ? deg[base + 1] : 0;
  int v2 = (base + 2 < n) ? deg[base + 2] : 0;
  int v3 = (base + 3 < n) ? deg[base + 3] : 0;
  int tot = v0 + v1 + v2 + v3;
  sh[tid] = tot;
  __syncthreads();
  for (int off = 1; off < 256; off <<= 1) {
    int y = (tid >= off) ? sh[tid - off] : 0;
    __syncthreads();
    sh[tid] += y;
    __syncthreads();
  }
  int excl = sh[tid] - tot;  // exclusive prefix of this thread's 4-chunk
  if (base + 0 < n) rowptr[base + 0] = excl;
  if (base + 1 < n) rowptr[base + 1] = excl + v0;
  if (base + 2 < n) rowptr[base + 2] = excl + v0 + v1;
  if (base + 3 < n) rowptr[base + 3] = excl + v0 + v1 + v2;
  if (tid == 255) bsums[blockIdx.x] = sh[255];
}

// exclusive scan of block sums (G <= 1024; here G = 98)
__global__ void k_scan2(int* __restrict__ bsums, int g) {
  __shared__ int sh[1024];
  int tid = threadIdx.x;
  int v = (tid < g) ? bsums[tid] : 0;
  sh[tid] = v;
  __syncthreads();
  for (int off = 1; off < 1024; off <<= 1) {
    int y = (tid >= off) ? sh[tid - off] : 0;
    __syncthreads();
    sh[tid] += y;
    __syncthreads();
  }
  if (tid < g) bsums[tid] = sh[tid] - v;
}

__global__ void k_scan3(int* __restrict__ rowptr, int* __restrict__ cursor,
                        const int* __restrict__ bsums, int n, int etot) {
  int i = blockIdx.x * 256 + threadIdx.x;
  if (i < n) {
    int v = rowptr[i] + bsums[i >> 10];
    rowptr[i] = v;
    cursor[i] = v;
  }
  if (i == 0) rowptr[n] = etot;
}

__global__ void k_scatter(const int* __restrict__ src, const int* __restrict__ dst,
                          int* __restrict__ cursor, int* __restrict__ sorted_src, int E) {
  int e = blockIdx.x * 256 + threadIdx.x;
  if (e < E) {
    int d = dst[e];
    int pos = atomicAdd(&cursor[d], 1);
    sorted_src[pos] = src[e];
  }
}

// ============================ mean aggregation (pull, wave per node) ============================
// One wave (64 lanes) per node; lane handles 2 channels (float2 -> 512B coalesced row read).
// Index-prefetch unroll x4 so the 4 dependent row loads pipeline.
__global__ void k_aggregate(const float* __restrict__ in, float* __restrict__ out,
                            const int* __restrict__ rowptr, const int* __restrict__ sorted_src,
                            int n) {
  int node = blockIdx.x * 4 + (threadIdx.x >> 6);
  if (node >= n) return;
  int lane = threadIdx.x & 63;
  int beg = rowptr[node], end = rowptr[node + 1];
  const float2* inp = (const float2*)in;
  float ax = 0.f, ay = 0.f;
  int e = beg;
  for (; e + 4 <= end; e += 4) {
    int s0 = sorted_src[e], s1 = sorted_src[e + 1], s2 = sorted_src[e + 2], s3 = sorted_src[e + 3];
    float2 v0 = inp[(size_t)s0 * 64 + lane];
    float2 v1 = inp[(size_t)s1 * 64 + lane];
    float2 v2 = inp[(size_t)s2 * 64 + lane];
    float2 v3 = inp[(size_t)s3 * 64 + lane];
    ax += (v0.x + v1.x) + (v2.x + v3.x);
    ay += (v0.y + v1.y) + (v2.y + v3.y);
  }
  for (; e < end; ++e) {
    int s = sorted_src[e];
    float2 v = inp[(size_t)s * 64 + lane];
    ax += v.x; ay += v.y;
  }
  int d = end - beg;
  float inv = (d > 0) ? (1.f / (float)d) : 0.f;  // mean with max(cnt,1): deg=0 -> 0 anyway
  ((float2*)out)[(size_t)node * 64 + lane] = make_float2(ax * inv, ay * inv);
}

// ============================ fused SAGE dual-GEMM ============================
// out[r] = relu(Am[r] @ Wl + bias + Ax[r] @ Wr)
// 256 threads, tile 128 rows x 128 cols, 8x8 outputs/thread, K staged in LDS chunks of 16.
// LDS: A transposed [k][row] pad 136 (conflict-free b128 row reads); W [k][col] pad 132.
__global__ __launch_bounds__(256, 2)
void k_sage(const float* __restrict__ Am, const float* __restrict__ Ax,
            const float* __restrict__ Wl, const float* __restrict__ Wr,
            const float* __restrict__ bias, float* __restrict__ out, int n) {
  __shared__ float sAm[TK][136];
  __shared__ float sAx[TK][136];
  __shared__ float sWl[TK][132];
  __shared__ float sWr[TK][132];
  int tid = threadIdx.x;
  int row0 = blockIdx.x * TM;
  int cg = tid & 15, rg = tid >> 4;
  int c0 = cg * 8, r0 = rg * 8;

  // staging maps
  int srow = tid & 127;        // 0..127
  int skq = tid >> 7;          // 0..1 -> k offset 0/8
  int wkl = tid >> 4;          // 0..15
  int wcq = (tid & 15) * 8;    // 0..120

  float acc[8][8];
#pragma unroll
  for (int i = 0; i < 8; i++)
#pragma unroll
    for (int j = 0; j < 8; j++) acc[i][j] = 0.f;

  int gr = row0 + srow;
  bool okrow = gr < n;
  const float* pAm = Am + (size_t)gr * CH;
  const float* pAx = Ax + (size_t)gr * CH;

  for (int k0 = 0; k0 < CH; k0 += TK) {
    // ---- stage A (transposed) ----
    int kk = skq * 8;
    float4 m0 = make_float4(0, 0, 0, 0), m1 = m0, x0 = m0, x1 = m0;
    if (okrow) {
      m0 = *(const float4*)(pAm + k0 + kk);
      m1 = *(const float4*)(pAm + k0 + kk + 4);
      x0 = *(const float4*)(pAx + k0 + kk);
      x1 = *(const float4*)(pAx + k0 + kk + 4);
    }
    // ---- stage W ----
    float4 wl0 = *(const float4*)(Wl + (size_t)(k0 + wkl) * CH + wcq);
    float4 wl1 = *(const float4*)(Wl + (size_t)(k0 + wkl) * CH + wcq + 4);
    float4 wr0 = *(const float4*)(Wr + (size_t)(k0 + wkl) * CH + wcq);
    float4 wr1 = *(const float4*)(Wr + (size_t)(k0 + wkl) * CH + wcq + 4);

    sAm[kk + 0][srow] = m0.x; sAm[kk + 1][srow] = m0.y; sAm[kk + 2][srow] = m0.z; sAm[kk + 3][srow] = m0.w;
    sAm[kk + 4][srow] = m1.x; sAm[kk + 5][srow] = m1.y; sAm[kk + 6][srow] = m1.z; sAm[kk + 7][srow] = m1.w;
    sAx[kk + 0][srow] = x0.x; sAx[kk + 1][srow] = x0.y; sAx[kk + 2][srow] = x0.z; sAx[kk + 3][srow] = x0.w;
    sAx[kk + 4][srow] = x1.x; sAx[kk + 5][srow] = x1.y; sAx[kk + 6][srow] = x1.z; sAx[kk + 7][srow] = x1.w;
    *(float4*)&sWl[wkl][wcq] = wl0;
    *(float4*)&sWl[wkl][wcq + 4] = wl1;
    *(float4*)&sWr[wkl][wcq] = wr0;
    *(float4*)&sWr[wkl][wcq + 4] = wr1;
    __syncthreads();

#pragma unroll
    for (int k = 0; k < TK; k++) {
      float4 a0 = *(const float4*)&sAm[k][r0];
      float4 a1 = *(const float4*)&sAm[k][r0 + 4];
      float4 b0 = *(const float4*)&sAx[k][r0];
      float4 b1 = *(const float4*)&sAx[k][r0 + 4];
      float4 l0 = *(const float4*)&sWl[k][c0];
      float4 l1 = *(const float4*)&sWl[k][c0 + 4];
      float4 q0 = *(const float4*)&sWr[k][c0];
      float4 q1 = *(const float4*)&sWr[k][c0 + 4];
      float am_[8] = {a0.x, a0.y, a0.z, a0.w, a1.x, a1.y, a1.z, a1.w};
      float ax_[8] = {b0.x, b0.y, b0.z, b0.w, b1.x, b1.y, b1.z, b1.w};
      float wl_[8] = {l0.x, l0.y, l0.z, l0.w, l1.x, l1.y, l1.z, l1.w};
      float wr_[8] = {q0.x, q0.y, q0.z, q0.w, q1.x, q1.y, q1.z, q1.w};
#pragma unroll
      for (int i = 0; i < 8; i++)
#pragma unroll
        for (int j = 0; j < 8; j++)
          acc[i][j] += am_[i] * wl_[j] + ax_[i] * wr_[j];
    }
    __syncthreads();
  }

  float4 bv0 = *(const float4*)&bias[c0];
  float4 bv1 = *(const float4*)&bias[c0 + 4];
  float bb[8] = {bv0.x, bv0.y, bv0.z, bv0.w, bv1.x, bv1.y, bv1.z, bv1.w};
#pragma unroll
  for (int i = 0; i < 8; i++) {
    int r = row0 + r0 + i;
    if (r < n) {
      float4 o0, o1;
      o0.x = fmaxf(acc[i][0] + bb[0], 0.f);
      o0.y = fmaxf(acc[i][1] + bb[1], 0.f);
      o0.z = fmaxf(acc[i][2] + bb[2], 0.f);
      o0.w = fmaxf(acc[i][3] + bb[3], 0.f);
      o1.x = fmaxf(acc[i][4] + bb[4], 0.f);
      o1.y = fmaxf(acc[i][5] + bb[5], 0.f);
      o1.z = fmaxf(acc[i][6] + bb[6], 0.f);
      o1.w = fmaxf(acc[i][7] + bb[7], 0.f);
      *(float4*)&out[(size_t)r * CH + c0] = o0;
      *(float4*)&out[(size_t)r * CH + c0 + 4] = o1;
    }
  }
}

// ============================ decoder GEMM ============================
// out[r] = alpha*(H[r] @ Wd + bd) + (1-alpha)*X[r]
__global__ __launch_bounds__(256, 2)
void k_decoder(const float* __restrict__ H, const float* __restrict__ Wd,
               const float* __restrict__ bd, const float* __restrict__ X,
               const float* __restrict__ alpha_p, float* __restrict__ out, int n) {
  __shared__ float sA[TK][136];
  __shared__ float sW[TK][132];
  int tid = threadIdx.x;
  int row0 = blockIdx.x * TM;
  int cg = tid & 15, rg = tid >> 4;
  int c0 = cg * 8, r0 = rg * 8;
  int srow = tid & 127;
  int skq = tid >> 7;
  int wkl = tid >> 4;
  int wcq = (tid & 15) * 8;

  float acc[8][8];
#pragma unroll
  for (int i = 0; i < 8; i++)
#pragma unroll
    for (int j = 0; j < 8; j++) acc[i][j] = 0.f;

  int gr = row0 + srow;
  bool okrow = gr < n;
  const float* pA = H + (size_t)gr * CH;

  for (int k0 = 0; k0 < CH; k0 += TK) {
    int kk = skq * 8;
    float4 m0 = make_float4(0, 0, 0, 0), m1 = m0;
    if (okrow) {
      m0 = *(const float4*)(pA + k0 + kk);
      m1 = *(const float4*)(pA + k0 + kk + 4);
    }
    float4 w0 = *(const float4*)(Wd + (size_t)(k0 + wkl) * CH + wcq);
    float4 w1 = *(const float4*)(Wd + (size_t)(k0 + wkl) * CH + wcq + 4);
    sA[kk + 0][srow] = m0.x; sA[kk + 1][srow] = m0.y; sA[kk + 2][srow] = m0.z; sA[kk + 3][srow] = m0.w;
    sA[kk + 4][srow] = m1.x; sA[kk + 5][srow] = m1.y; sA[kk + 6][srow] = m1.z; sA[kk + 7][srow] = m1.w;
    *(float4*)&sW[wkl][wcq] = w0;
    *(float4*)&sW[wkl][wcq + 4] = w1;
    __syncthreads();

#pragma unroll
    for (int k = 0; k < TK; k++) {
      float4 a0 = *(const float4*)&sA[k][r0];
      float4 a1 = *(const float4*)&sA[k][r0 + 4];
      float4 l0 = *(const float4*)&sW[k][c0];
      float4 l1 = *(const float4*)&sW[k][c0 + 4];
      float am_[8] = {a0.x, a0.y, a0.z, a0.w, a1.x, a1.y, a1.z, a1.w};
      float wl_[8] = {l0.x, l0.y, l0.z, l0.w, l1.x, l1.y, l1.z, l1.w};
#pragma unroll
      for (int i = 0; i < 8; i++)
#pragma unroll
        for (int j = 0; j < 8; j++)
          acc[i][j] += am_[i] * wl_[j];
    }
    __syncthreads();
  }

  float al = alpha_p[0];
  float be = 1.f - al;
  float4 bv0 = *(const float4*)&bd[c0];
  float4 bv1 = *(const float4*)&bd[c0 + 4];
  float bb[8] = {bv0.x, bv0.y, bv0.z, bv0.w, bv1.x, bv1.y, bv1.z, bv1.w};
#pragma unroll
  for (int i = 0; i < 8; i++) {
    int r = row0 + r0 + i;
    if (r < n) {
      float4 xv0 = *(const float4*)&X[(size_t)r * CH + c0];
      float4 xv1 = *(const float4*)&X[(size_t)r * CH + c0 + 4];
      float4 o0, o1;
      o0.x = al * (acc[i][0] + bb[0]) + be * xv0.x;
      o0.y = al * (acc[i][1] + bb[1]) + be * xv0.y;
      o0.z = al * (acc[i][2] + bb[2]) + be * xv0.z;
      o0.w = al * (acc[i][3] + bb[3]) + be * xv0.w;
      o1.x = al * (acc[i][4] + bb[4]) + be * xv1.x;
      o1.y = al * (acc[i][5] + bb[5]) + be * xv1.y;
      o1.z = al * (acc[i][6] + bb[6]) + be * xv1.z;
      o1.w = al * (acc[i][7] + bb[7]) + be * xv1.w;
      *(float4*)&out[(size_t)r * CH + c0] = o0;
      *(float4*)&out[(size_t)r * CH + c0 + 4] = o1;
    }
  }
}

// ============================ launch ============================

extern "C" void kernel_launch(void* const* d_in, const int* in_sizes, int n_in,
                              void* d_out, int out_size, void* d_ws, size_t ws_size,
                              hipStream_t stream) {
  const float* x   = (const float*)d_in[0];
  const int*   ei  = (const int*)d_in[1];
  const float* W1l = (const float*)d_in[2];
  const float* b1  = (const float*)d_in[3];
  const float* W1r = (const float*)d_in[4];
  const float* W2l = (const float*)d_in[5];
  const float* b2  = (const float*)d_in[6];
  const float* W2r = (const float*)d_in[7];
  const float* Wd  = (const float*)d_in[8];
  const float* bd  = (const float*)d_in[9];
  const float* alp = (const float*)d_in[10];

  int N = in_sizes[0] / CH;   // 100000
  int E = in_sizes[1] / 2;    // 1600000
  const int* src = ei;
  const int* dst = ei + E;

  // workspace layout (512B-aligned): ~59 MB total
  char* ws = (char*)d_ws;
  size_t off = 0;
  auto alloc = [&](size_t bytes) -> char* {
    off = (off + 511) & ~size_t(511);
    char* p = ws + off;
    off += bytes;
    return p;
  };
  int*   deg    = (int*)alloc((size_t)N * 4);
  int*   rowptr = (int*)alloc((size_t)(N + 1) * 4);
  int*   cursor = (int*)alloc((size_t)N * 4);
  int*   bsums  = (int*)alloc(4096);
  int*   sorted = (int*)alloc((size_t)E * 4);
  float* h      = (float*)alloc((size_t)N * CH * 4);
  float* mean   = (float*)d_out;  // d_out doubles as the mean scratch; decoder overwrites it last

  hipMemsetAsync(deg, 0, (size_t)N * 4, stream);
  int gE = (E + 255) / 256;
  int G  = (N + 1023) / 1024;  // 98 (<=1024 required by k_scan2)
  k_hist<<<gE, 256, 0, stream>>>(dst, deg, E);
  k_scan1<<<G, 256, 0, stream>>>(deg, rowptr, bsums, N);
  k_scan2<<<1, 1024, 0, stream>>>(bsums, G);
  k_scan3<<<(N + 255) / 256, 256, 0, stream>>>(rowptr, cursor, bsums, N, E);
  k_scatter<<<gE, 256, 0, stream>>>(src, dst, cursor, sorted, E);

  int gAgg  = (N + 3) / 4;
  int gGemm = (N + TM - 1) / TM;
  // layer 1: mean(x) -> d_out; h1 = relu(mean@W1l + b1 + x@W1r)
  k_aggregate<<<gAgg, 256, 0, stream>>>(x, mean, rowptr, sorted, N);
  k_sage<<<gGemm, 256, 0, stream>>>(mean, x, W1l, W1r, b1, h, N);
  // layer 2: mean(h1) -> d_out; h2 = relu(mean@W2l + b2 + h1@W2r)  (in-place over h, row-local)
  k_aggregate<<<gAgg, 256, 0, stream>>>(h, mean, rowptr, sorted, N);
  k_sage<<<gGemm, 256, 0, stream>>>(mean, h, W2l, W2r, b2, h, N);
  // decoder: d_out = alpha*(h2@Wd + bd) + (1-alpha)*x
  k_decoder<<<gGemm, 256, 0, stream>>>(h, Wd, bd, x, alp, (float*)d_out, N);
}

// Round 2
// 565.785 us; speedup vs baseline: 4.4992x; 4.4992x over previous
//
#include <hip/hip_runtime.h>
#include <cstddef>
#include <cstdint>

#define CH 128   // IN_CH == HID_CH == 128

typedef __attribute__((ext_vector_type(8))) short short8;
typedef __attribute__((ext_vector_type(4))) float f32x4;

__device__ __forceinline__ unsigned short f2bf(float f) {
  unsigned u = __float_as_uint(f);
  u += 0x7FFF + ((u >> 16) & 1);   // round-to-nearest-even
  return (unsigned short)(u >> 16);
}
__device__ __forceinline__ float bf2f(unsigned int h) {
  return __uint_as_float(h << 16);
}
__device__ __forceinline__ void gld16(const void* g, void* l) {
  __builtin_amdgcn_global_load_lds((const __attribute__((address_space(1))) unsigned int*)g,
                                   (__attribute__((address_space(3))) unsigned int*)l, 16, 0, 0);
}

// ============================ fp32 -> bf16 convert (x) ============================
__global__ void k_cvt(const float4* __restrict__ in, uint4* __restrict__ out, int n8) {
  int i = blockIdx.x * 256 + threadIdx.x;   // 8 elements per thread
  if (i < n8) {
    float4 a = in[i * 2], b = in[i * 2 + 1];
    uint4 o;
    o.x = (unsigned)f2bf(a.x) | ((unsigned)f2bf(a.y) << 16);
    o.y = (unsigned)f2bf(a.z) | ((unsigned)f2bf(a.w) << 16);
    o.z = (unsigned)f2bf(b.x) | ((unsigned)f2bf(b.y) << 16);
    o.w = (unsigned)f2bf(b.z) | ((unsigned)f2bf(b.w) << 16);
    out[i] = o;
  }
}

// ============================ weight transpose + bf16 (5 matrices) ============================
// dst[m] = W_m^T as bf16, layout [n][k] (k contiguous) -> MFMA B-operand loads are ds_read_b128
__global__ void k_wt(const float* __restrict__ w0, const float* __restrict__ w1,
                     const float* __restrict__ w2, const float* __restrict__ w3,
                     const float* __restrict__ w4, unsigned short* __restrict__ dst) {
  const float* srcs[5] = {w0, w1, w2, w3, w4};
  const float* w = srcs[blockIdx.x];
  unsigned short* d = dst + (size_t)blockIdx.x * CH * CH;
  for (int idx = threadIdx.x; idx < CH * CH; idx += 256) {
    int k = idx >> 7, nn = idx & 127;
    d[nn * CH + k] = f2bf(w[idx]);   // coalesced read, scattered 2B write (32KB total, one-time)
  }
}

// ============================ CSR build (counting sort by dst) ============================
__global__ void k_hist(const int* __restrict__ dst, int* __restrict__ deg, int E) {
  int e = blockIdx.x * 256 + threadIdx.x;
  if (e < E) atomicAdd(&deg[dst[e]], 1);
}

__global__ void k_scan1(const int* __restrict__ deg, int* __restrict__ rowptr,
                        int* __restrict__ bsums, int n) {
  __shared__ int sh[256];
  int tid = threadIdx.x;
  int base = blockIdx.x * 1024 + tid * 4;
  int v0 = (base + 0 < n) ? deg[base + 0] : 0;
  int v1 = (base + 1 < n) ? deg[base + 1] : 0;
  int v2 = (base + 2 < n) ? deg[base + 2] : 0;
  int v3 = (base + 3 < n) ? deg[base + 3] : 0;
  int tot = v0 + v1 + v2 + v3;
  sh[tid] = tot;
  __syncthreads();
  for (int off = 1; off < 256; off <<= 1) {
    int y = (tid >= off) ? sh[tid - off] : 0;
    __syncthreads();
    sh[tid] += y;
    __syncthreads();
  }
  int excl = sh[tid] - tot;
  if (base + 0 < n) rowptr[base + 0] = excl;
  if (base + 1 < n) rowptr[base + 1] = excl + v0;
  if (base + 2 < n) rowptr[base + 2] = excl + v0 + v1;
  if (base + 3 < n) rowptr[base + 3] = excl + v0 + v1 + v2;
  if (tid == 255) bsums[blockIdx.x] = sh[255];
}

__global__ void k_scan2(int* __restrict__ bsums, int g) {
  __shared__ int sh[1024];
  int tid = threadIdx.x;
  int v = (tid < g) ? bsums[tid] : 0;
  sh[tid] = v;
  __syncthreads();
  for (int off = 1; off < 1024; off <<= 1) {
    int y = (tid >= off) ? sh[tid - off] : 0;
    __syncthreads();
    sh[tid] += y;
    __syncthreads();
  }
  if (tid < g) bsums[tid] = sh[tid] - v;
}

__global__ void k_scan3(int* __restrict__ rowptr, int* __restrict__ cursor,
                        const int* __restrict__ bsums, int n, int etot) {
  int i = blockIdx.x * 256 + threadIdx.x;
  if (i < n) {
    int v = rowptr[i] + bsums[i >> 10];
    rowptr[i] = v;
    cursor[i] = v;
  }
  if (i == 0) rowptr[n] = etot;
}

__global__ void k_scatter(const int* __restrict__ src, const int* __restrict__ dst,
                          int* __restrict__ cursor, int* __restrict__ sorted_src, int E) {
  int e = blockIdx.x * 256 + threadIdx.x;
  if (e < E) {
    int d = dst[e];
    int pos = atomicAdd(&cursor[d], 1);
    sorted_src[pos] = src[e];
  }
}

// ============================ mean aggregation (bf16 in/out, wave per node) ============================
// Lane handles 2 channels (packed uint = 2 bf16, 4B/lane -> 256B coalesced row read).
__global__ void k_agg(const unsigned short* __restrict__ in, unsigned short* __restrict__ out,
                      const int* __restrict__ rowptr, const int* __restrict__ sorted_src,
                      int n) {
  int node = blockIdx.x * 4 + (threadIdx.x >> 6);
  if (node >= n) return;
  int lane = threadIdx.x & 63;
  int beg = rowptr[node], end = rowptr[node + 1];
  const unsigned int* inp = (const unsigned int*)in;
  float ax = 0.f, ay = 0.f;
  int e = beg;
  for (; e + 4 <= end; e += 4) {
    int s0 = sorted_src[e], s1 = sorted_src[e + 1], s2 = sorted_src[e + 2], s3 = sorted_src[e + 3];
    unsigned int v0 = inp[(size_t)s0 * 64 + lane];
    unsigned int v1 = inp[(size_t)s1 * 64 + lane];
    unsigned int v2 = inp[(size_t)s2 * 64 + lane];
    unsigned int v3 = inp[(size_t)s3 * 64 + lane];
    ax += (bf2f(v0 & 0xffff) + bf2f(v1 & 0xffff)) + (bf2f(v2 & 0xffff) + bf2f(v3 & 0xffff));
    ay += (bf2f(v0 >> 16) + bf2f(v1 >> 16)) + (bf2f(v2 >> 16) + bf2f(v3 >> 16));
  }
  for (; e < end; ++e) {
    unsigned int v = inp[(size_t)sorted_src[e] * 64 + lane];
    ax += bf2f(v & 0xffff);
    ay += bf2f(v >> 16);
  }
  int d = end - beg;
  float inv = (d > 0) ? (1.f / (float)d) : 0.f;
  ((unsigned int*)out)[(size_t)node * 64 + lane] =
      (unsigned)f2bf(ax * inv) | ((unsigned)f2bf(ay * inv) << 16);
}

// ============================ fused SAGE dual-GEMM via MFMA bf16 ============================
// out = relu(Am @ Wl + bias + Ax @ Wr), all operands bf16, fp32 accumulate.
// Treated as one GEMM with K=256 over 4 K-chunks of 64: (Am,WTl,0),(Am,WTl,64),(Ax,WTr,0),(Ax,WTr,64).
// Block: 128 rows x 128 cols, 4 waves; wave w owns rows [w*32, w*32+32) x all 128 cols
// -> 2x8 MFMA tiles (16x16x32), acc = 64 VGPRs/lane.
__global__ __launch_bounds__(256, 2)
void k_sage(const unsigned short* __restrict__ Am, const unsigned short* __restrict__ Ax,
            const unsigned short* __restrict__ WTl, const unsigned short* __restrict__ WTr,
            const float* __restrict__ bias, unsigned short* __restrict__ out, int n) {
  __shared__ unsigned short sA[128 * 64];   // [row][k] k-contiguous, 16 KB
  __shared__ unsigned short sB[128 * 64];   // [n][k]   k-contiguous, 16 KB
  int tid = threadIdx.x;
  int lane = tid & 63;
  int w = tid >> 6;
  int row0 = blockIdx.x * 128;
  int col_lo = lane & 15, quad = lane >> 4;

  f32x4 acc[2][8];
#pragma unroll
  for (int mt = 0; mt < 2; mt++)
#pragma unroll
    for (int nt = 0; nt < 8; nt++) acc[mt][nt] = (f32x4){0.f, 0.f, 0.f, 0.f};

  const unsigned short* As[4] = {Am, Am, Ax, Ax};
  const unsigned short* Bs[4] = {WTl, WTl, WTr, WTr};
  const int k0s[4] = {0, 64, 0, 64};

  for (int c = 0; c < 4; c++) {
    const unsigned short* Ap = As[c];
    const unsigned short* Bp = Bs[c];
    int k0 = k0s[c];
    // stage: 1024 x 16B loads for each of A,B; 256 threads x 4 iters
#pragma unroll
    for (int it = 0; it < 4; it++) {
      int flat = it * 256 + tid;
      int r = flat >> 3;
      int kof = (flat & 7) * 8;
      int gr = row0 + r;
      if (gr > n - 1) gr = n - 1;   // clamp: dead rows load valid data, never stored
      gld16(Ap + (size_t)gr * CH + k0 + kof, sA + flat * 8);
      gld16(Bp + (size_t)r * CH + k0 + kof, sB + flat * 8);
    }
    __syncthreads();   // compiler emits vmcnt(0) drain before barrier

#pragma unroll
    for (int ks = 0; ks < 2; ks++) {
      short8 a0 = *(const short8*)&sA[(w * 32 + col_lo) * 64 + ks * 32 + quad * 8];
      short8 a1 = *(const short8*)&sA[(w * 32 + 16 + col_lo) * 64 + ks * 32 + quad * 8];
      short8 b[8];
#pragma unroll
      for (int nt = 0; nt < 8; nt++)
        b[nt] = *(const short8*)&sB[(nt * 16 + col_lo) * 64 + ks * 32 + quad * 8];
#pragma unroll
      for (int nt = 0; nt < 8; nt++) {
        acc[0][nt] = __builtin_amdgcn_mfma_f32_16x16x32_bf16(a0, b[nt], acc[0][nt], 0, 0, 0);
        acc[1][nt] = __builtin_amdgcn_mfma_f32_16x16x32_bf16(a1, b[nt], acc[1][nt], 0, 0, 0);
      }
    }
    __syncthreads();
  }

  // epilogue: C/D layout col=lane&15, row=quad*4+reg  [m89-verified]
#pragma unroll
  for (int nt = 0; nt < 8; nt++) {
    float bb = bias[nt * 16 + col_lo];
#pragma unroll
    for (int mt = 0; mt < 2; mt++) {
#pragma unroll
      for (int r = 0; r < 4; r++) {
        int rr = row0 + w * 32 + mt * 16 + quad * 4 + r;
        if (rr < n) {
          float v = fmaxf(acc[mt][nt][r] + bb, 0.f);
          out[(size_t)rr * CH + nt * 16 + col_lo] = f2bf(v);
        }
      }
    }
  }
}

// ============================ decoder GEMM via MFMA ============================
// out = alpha*(H @ Wd + bd) + (1-alpha)*X   (H bf16, X/out fp32)
__global__ __launch_bounds__(256, 2)
void k_dec(const unsigned short* __restrict__ H, const unsigned short* __restrict__ WTd,
           const float* __restrict__ bd, const float* __restrict__ X,
           const float* __restrict__ alpha_p, float* __restrict__ out, int n) {
  __shared__ unsigned short sA[128 * 64];
  __shared__ unsigned short sB[128 * 64];
  int tid = threadIdx.x;
  int lane = tid & 63;
  int w = tid >> 6;
  int row0 = blockIdx.x * 128;
  int col_lo = lane & 15, quad = lane >> 4;

  f32x4 acc[2][8];
#pragma unroll
  for (int mt = 0; mt < 2; mt++)
#pragma unroll
    for (int nt = 0; nt < 8; nt++) acc[mt][nt] = (f32x4){0.f, 0.f, 0.f, 0.f};

  for (int c = 0; c < 2; c++) {
    int k0 = c * 64;
#pragma unroll
    for (int it = 0; it < 4; it++) {
      int flat = it * 256 + tid;
      int r = flat >> 3;
      int kof = (flat & 7) * 8;
      int gr = row0 + r;
      if (gr > n - 1) gr = n - 1;
      gld16(H + (size_t)gr * CH + k0 + kof, sA + flat * 8);
      gld16(WTd + (size_t)r * CH + k0 + kof, sB + flat * 8);
    }
    __syncthreads();

#pragma unroll
    for (int ks = 0; ks < 2; ks++) {
      short8 a0 = *(const short8*)&sA[(w * 32 + col_lo) * 64 + ks * 32 + quad * 8];
      short8 a1 = *(const short8*)&sA[(w * 32 + 16 + col_lo) * 64 + ks * 32 + quad * 8];
      short8 b[8];
#pragma unroll
      for (int nt = 0; nt < 8; nt++)
        b[nt] = *(const short8*)&sB[(nt * 16 + col_lo) * 64 + ks * 32 + quad * 8];
#pragma unroll
      for (int nt = 0; nt < 8; nt++) {
        acc[0][nt] = __builtin_amdgcn_mfma_f32_16x16x32_bf16(a0, b[nt], acc[0][nt], 0, 0, 0);
        acc[1][nt] = __builtin_amdgcn_mfma_f32_16x16x32_bf16(a1, b[nt], acc[1][nt], 0, 0, 0);
      }
    }
    __syncthreads();
  }

  float al = alpha_p[0];
  float be = 1.f - al;
#pragma unroll
  for (int nt = 0; nt < 8; nt++) {
    float bb = bd[nt * 16 + col_lo];
#pragma unroll
    for (int mt = 0; mt < 2; mt++) {
#pragma unroll
      for (int r = 0; r < 4; r++) {
        int rr = row0 + w * 32 + mt * 16 + quad * 4 + r;
        if (rr < n) {
          int cc = nt * 16 + col_lo;
          float xv = X[(size_t)rr * CH + cc];
          out[(size_t)rr * CH + cc] = al * (acc[mt][nt][r] + bb) + be * xv;
        }
      }
    }
  }
}

// ============================ launch ============================

extern "C" void kernel_launch(void* const* d_in, const int* in_sizes, int n_in,
                              void* d_out, int out_size, void* d_ws, size_t ws_size,
                              hipStream_t stream) {
  const float* x   = (const float*)d_in[0];
  const int*   ei  = (const int*)d_in[1];
  const float* W1l = (const float*)d_in[2];
  const float* b1  = (const float*)d_in[3];
  const float* W1r = (const float*)d_in[4];
  const float* W2l = (const float*)d_in[5];
  const float* b2  = (const float*)d_in[6];
  const float* W2r = (const float*)d_in[7];
  const float* Wd  = (const float*)d_in[8];
  const float* bd  = (const float*)d_in[9];
  const float* alp = (const float*)d_in[10];

  int N = in_sizes[0] / CH;   // 100000
  int E = in_sizes[1] / 2;    // 1600000
  const int* src = ei;
  const int* dst = ei + E;

  char* ws = (char*)d_ws;
  size_t off = 0;
  auto alloc = [&](size_t bytes) -> char* {
    off = (off + 511) & ~size_t(511);
    char* p = ws + off;
    off += bytes;
    return p;
  };
  int*   deg    = (int*)alloc((size_t)N * 4);
  int*   rowptr = (int*)alloc((size_t)(N + 1) * 4);
  int*   cursor = (int*)alloc((size_t)N * 4);
  int*   bsums  = (int*)alloc(4096);
  int*   sorted = (int*)alloc((size_t)E * 4);
  unsigned short* xb = (unsigned short*)alloc((size_t)N * CH * 2);   // x as bf16
  unsigned short* h  = (unsigned short*)alloc((size_t)N * CH * 2);   // hidden, bf16
  unsigned short* WT = (unsigned short*)alloc((size_t)5 * CH * CH * 2); // transposed bf16 weights
  unsigned short* mean = (unsigned short*)d_out;  // alias: decoder fully overwrites d_out last

  hipMemsetAsync(deg, 0, (size_t)N * 4, stream);
  int gE = (E + 255) / 256;
  int G  = (N + 1023) / 1024;   // 98 (<=1024 required by k_scan2)
  k_cvt<<<(N * CH / 8 + 255) / 256, 256, 0, stream>>>((const float4*)x, (uint4*)xb, N * CH / 8);
  k_wt<<<5, 256, 0, stream>>>(W1l, W1r, W2l, W2r, Wd, WT);
  k_hist<<<gE, 256, 0, stream>>>(dst, deg, E);
  k_scan1<<<G, 256, 0, stream>>>(deg, rowptr, bsums, N);
  k_scan2<<<1, 1024, 0, stream>>>(bsums, G);
  k_scan3<<<(N + 255) / 256, 256, 0, stream>>>(rowptr, cursor, bsums, N, E);
  k_scatter<<<gE, 256, 0, stream>>>(src, dst, cursor, sorted, E);

  int gAgg  = (N + 3) / 4;
  int gGemm = (N + 127) / 128;
  unsigned short* WT1l = WT + 0 * CH * CH;
  unsigned short* WT1r = WT + 1 * CH * CH;
  unsigned short* WT2l = WT + 2 * CH * CH;
  unsigned short* WT2r = WT + 3 * CH * CH;
  unsigned short* WTd  = WT + 4 * CH * CH;

  // layer 1: mean(xb) -> mean; h1 = relu(mean@W1l + b1 + xb@W1r)
  k_agg<<<gAgg, 256, 0, stream>>>(xb, mean, rowptr, sorted, N);
  k_sage<<<gGemm, 256, 0, stream>>>(mean, xb, WT1l, WT1r, b1, h, N);
  // layer 2: mean(h1) -> mean; h2 = relu(mean@W2l + b2 + h1@W2r)  (in-place, row-local)
  k_agg<<<gAgg, 256, 0, stream>>>(h, mean, rowptr, sorted, N);
  k_sage<<<gGemm, 256, 0, stream>>>(mean, h, WT2l, WT2r, b2, h, N);
  // decoder: d_out = alpha*(h2@Wd + bd) + (1-alpha)*x
  k_dec<<<gGemm, 256, 0, stream>>>(h, WTd, bd, x, alp, (float*)d_out, N);
}

// Round 3
// 452.573 us; speedup vs baseline: 5.6246x; 1.2502x over previous
//
#include <hip/hip_runtime.h>
#include <cstddef>
#include <cstdint>

#define CH 128     // IN_CH == HID_CH == 128
#define NBKT 196   // dst >> 9 -> buckets 0..195 (512 nodes each)
#define ABLK 320   // phase-A blocks
#define BKT_NODES 512

typedef __attribute__((ext_vector_type(8))) short short8;
typedef __attribute__((ext_vector_type(4))) float f32x4;

__device__ __forceinline__ unsigned short f2bf(float f) {
  unsigned u = __float_as_uint(f);
  u += 0x7FFF + ((u >> 16) & 1);   // round-to-nearest-even
  return (unsigned short)(u >> 16);
}
__device__ __forceinline__ float bf2f(unsigned int h) {
  return __uint_as_float(h << 16);
}
__device__ __forceinline__ void gld16(const void* g, void* l) {
  __builtin_amdgcn_global_load_lds((const __attribute__((address_space(1))) unsigned int*)g,
                                   (__attribute__((address_space(3))) unsigned int*)l, 16, 0, 0);
}

// ============================ fp32 -> bf16 convert (x) ============================
__global__ void k_cvt(const float4* __restrict__ in, uint4* __restrict__ out, int n8) {
  int i = blockIdx.x * 256 + threadIdx.x;   // 8 elements per thread
  if (i < n8) {
    float4 a = in[i * 2], b = in[i * 2 + 1];
    uint4 o;
    o.x = (unsigned)f2bf(a.x) | ((unsigned)f2bf(a.y) << 16);
    o.y = (unsigned)f2bf(a.z) | ((unsigned)f2bf(a.w) << 16);
    o.z = (unsigned)f2bf(b.x) | ((unsigned)f2bf(b.y) << 16);
    o.w = (unsigned)f2bf(b.z) | ((unsigned)f2bf(b.w) << 16);
    out[i] = o;
  }
}

// ============================ weight transpose + bf16 (5 matrices) ============================
__global__ void k_wt(const float* __restrict__ w0, const float* __restrict__ w1,
                     const float* __restrict__ w2, const float* __restrict__ w3,
                     const float* __restrict__ w4, unsigned short* __restrict__ dst) {
  const float* srcs[5] = {w0, w1, w2, w3, w4};
  const float* w = srcs[blockIdx.x];
  unsigned short* d = dst + (size_t)blockIdx.x * CH * CH;
  for (int idx = threadIdx.x; idx < CH * CH; idx += 256) {
    int k = idx >> 7, nn = idx & 127;
    d[nn * CH + k] = f2bf(w[idx]);
  }
}

// ============================ sort phase A: bin by dst>>9 (no device atomics) ============================
// A1: per-block LDS histogram of its edge chunk; counts -> cnt[bucket*ABLK + block]
__global__ void k_bhist(const int* __restrict__ dst, int* __restrict__ cnt, int E, int chunk) {
  __shared__ int c[NBKT];
  for (int i = threadIdx.x; i < NBKT; i += 256) c[i] = 0;
  __syncthreads();
  int s = blockIdx.x * chunk;
  int e = min(s + chunk, E);
  for (int i = s + threadIdx.x; i < e; i += 256)
    atomicAdd(&c[dst[i] >> 9], 1);
  __syncthreads();
  for (int i = threadIdx.x; i < NBKT; i += 256)
    cnt[i * ABLK + blockIdx.x] = c[i];
}

// A3: re-read chunk, scatter packed records into per-(bucket,block) contiguous runs.
// record = src (17b) | dst_local (9b) << 17   (src < 131072, dst_local < 512)
__global__ void k_bin(const int* __restrict__ src, const int* __restrict__ dst,
                      const int* __restrict__ ofs, unsigned int* __restrict__ binned,
                      int E, int chunk) {
  __shared__ int cur[NBKT];
  for (int i = threadIdx.x; i < NBKT; i += 256) cur[i] = ofs[i * ABLK + blockIdx.x];
  __syncthreads();
  int s = blockIdx.x * chunk;
  int e = min(s + chunk, E);
  for (int i = s + threadIdx.x; i < e; i += 256) {
    int d = dst[i];
    int b = d >> 9;
    int pos = atomicAdd(&cur[b], 1);   // LDS atomic
    binned[pos] = (unsigned)src[i] | ((unsigned)(d & 511) << 17);
  }
}

// ============================ sort phase B ============================
// B1: per-bucket degree histogram (replaces global-atomic k_hist), coalesced deg write
__global__ void k_deg(const unsigned int* __restrict__ binned, const int* __restrict__ ofs,
                      int* __restrict__ deg, int N) {
  __shared__ int c[BKT_NODES];
  int b = blockIdx.x;
  for (int i = threadIdx.x; i < BKT_NODES; i += 256) c[i] = 0;
  __syncthreads();
  int s = ofs[b * ABLK];
  int e = ofs[(b + 1) * ABLK];   // last bucket: ofs[NBKT*ABLK] == E
  for (int i = s + threadIdx.x; i < e; i += 256)
    atomicAdd(&c[binned[i] >> 17], 1);
  __syncthreads();
  int base = b * BKT_NODES;
  for (int i = threadIdx.x; i < BKT_NODES; i += 256)
    if (base + i < N) deg[base + i] = c[i];
}

// B2: final scatter; random 4B writes confined to one bucket's ~32KB span, single block/XCD
__global__ void k_sort(const unsigned int* __restrict__ binned, const int* __restrict__ ofs,
                       const int* __restrict__ rowptr, int* __restrict__ sorted, int N) {
  __shared__ int cur[BKT_NODES];
  int b = blockIdx.x;
  int base = b * BKT_NODES;
  for (int i = threadIdx.x; i < BKT_NODES; i += 256)
    cur[i] = (base + i < N) ? rowptr[base + i] : 0;
  __syncthreads();
  int s = ofs[b * ABLK];
  int e = ofs[(b + 1) * ABLK];
  for (int i = s + threadIdx.x; i < e; i += 256) {
    unsigned w = binned[i];
    int dl = w >> 17;
    int pos = atomicAdd(&cur[dl], 1);   // LDS atomic
    sorted[pos] = w & 0x1FFFF;
  }
}

// ============================ generic scan chain (1024 elems/block) ============================
__global__ void k_scan1(const int* __restrict__ deg, int* __restrict__ rowptr,
                        int* __restrict__ bsums, int n) {
  __shared__ int sh[256];
  int tid = threadIdx.x;
  int base = blockIdx.x * 1024 + tid * 4;
  int v0 = (base + 0 < n) ? deg[base + 0] : 0;
  int v1 = (base + 1 < n) ? deg[base + 1] : 0;
  int v2 = (base + 2 < n) ? deg[base + 2] : 0;
  int v3 = (base + 3 < n) ? deg[base + 3] : 0;
  int tot = v0 + v1 + v2 + v3;
  sh[tid] = tot;
  __syncthreads();
  for (int off = 1; off < 256; off <<= 1) {
    int y = (tid >= off) ? sh[tid - off] : 0;
    __syncthreads();
    sh[tid] += y;
    __syncthreads();
  }
  int excl = sh[tid] - tot;
  if (base + 0 < n) rowptr[base + 0] = excl;
  if (base + 1 < n) rowptr[base + 1] = excl + v0;
  if (base + 2 < n) rowptr[base + 2] = excl + v0 + v1;
  if (base + 3 < n) rowptr[base + 3] = excl + v0 + v1 + v2;
  if (tid == 255) bsums[blockIdx.x] = sh[255];
}

__global__ void k_scan2(int* __restrict__ bsums, int g) {
  __shared__ int sh[1024];
  int tid = threadIdx.x;
  int v = (tid < g) ? bsums[tid] : 0;
  sh[tid] = v;
  __syncthreads();
  for (int off = 1; off < 1024; off <<= 1) {
    int y = (tid >= off) ? sh[tid - off] : 0;
    __syncthreads();
    sh[tid] += y;
    __syncthreads();
  }
  if (tid < g) bsums[tid] = sh[tid] - v;
}

__global__ void k_scan3(int* __restrict__ arr, const int* __restrict__ bsums, int n, int total) {
  int i = blockIdx.x * 256 + threadIdx.x;
  if (i < n) arr[i] += bsums[i >> 10];
  if (i == 0) arr[n] = total;
}

// ============================ mean aggregation (bf16 in/out, wave per node) ============================
__global__ void k_agg(const unsigned short* __restrict__ in, unsigned short* __restrict__ out,
                      const int* __restrict__ rowptr, const int* __restrict__ sorted_src,
                      int n) {
  int node = blockIdx.x * 4 + (threadIdx.x >> 6);
  if (node >= n) return;
  int lane = threadIdx.x & 63;
  int beg = rowptr[node], end = rowptr[node + 1];
  const unsigned int* inp = (const unsigned int*)in;
  float ax = 0.f, ay = 0.f;
  int e = beg;
  for (; e + 4 <= end; e += 4) {
    int s0 = sorted_src[e], s1 = sorted_src[e + 1], s2 = sorted_src[e + 2], s3 = sorted_src[e + 3];
    unsigned int v0 = inp[(size_t)s0 * 64 + lane];
    unsigned int v1 = inp[(size_t)s1 * 64 + lane];
    unsigned int v2 = inp[(size_t)s2 * 64 + lane];
    unsigned int v3 = inp[(size_t)s3 * 64 + lane];
    ax += (bf2f(v0 & 0xffff) + bf2f(v1 & 0xffff)) + (bf2f(v2 & 0xffff) + bf2f(v3 & 0xffff));
    ay += (bf2f(v0 >> 16) + bf2f(v1 >> 16)) + (bf2f(v2 >> 16) + bf2f(v3 >> 16));
  }
  for (; e < end; ++e) {
    unsigned int v = inp[(size_t)sorted_src[e] * 64 + lane];
    ax += bf2f(v & 0xffff);
    ay += bf2f(v >> 16);
  }
  int d = end - beg;
  float inv = (d > 0) ? (1.f / (float)d) : 0.f;
  ((unsigned int*)out)[(size_t)node * 64 + lane] =
      (unsigned)f2bf(ax * inv) | ((unsigned)f2bf(ay * inv) << 16);
}

// ============================ fused SAGE dual-GEMM via MFMA bf16 ============================
__global__ __launch_bounds__(256, 2)
void k_sage(const unsigned short* __restrict__ Am, const unsigned short* __restrict__ Ax,
            const unsigned short* __restrict__ WTl, const unsigned short* __restrict__ WTr,
            const float* __restrict__ bias, unsigned short* __restrict__ out, int n) {
  __shared__ unsigned short sA[128 * 64];
  __shared__ unsigned short sB[128 * 64];
  int tid = threadIdx.x;
  int lane = tid & 63;
  int w = tid >> 6;
  int row0 = blockIdx.x * 128;
  int col_lo = lane & 15, quad = lane >> 4;

  f32x4 acc[2][8];
#pragma unroll
  for (int mt = 0; mt < 2; mt++)
#pragma unroll
    for (int nt = 0; nt < 8; nt++) acc[mt][nt] = (f32x4){0.f, 0.f, 0.f, 0.f};

  const unsigned short* As[4] = {Am, Am, Ax, Ax};
  const unsigned short* Bs[4] = {WTl, WTl, WTr, WTr};
  const int k0s[4] = {0, 64, 0, 64};

  for (int c = 0; c < 4; c++) {
    const unsigned short* Ap = As[c];
    const unsigned short* Bp = Bs[c];
    int k0 = k0s[c];
#pragma unroll
    for (int it = 0; it < 4; it++) {
      int flat = it * 256 + tid;
      int r = flat >> 3;
      int kof = (flat & 7) * 8;
      int gr = row0 + r;
      if (gr > n - 1) gr = n - 1;
      gld16(Ap + (size_t)gr * CH + k0 + kof, sA + flat * 8);
      gld16(Bp + (size_t)r * CH + k0 + kof, sB + flat * 8);
    }
    __syncthreads();

#pragma unroll
    for (int ks = 0; ks < 2; ks++) {
      short8 a0 = *(const short8*)&sA[(w * 32 + col_lo) * 64 + ks * 32 + quad * 8];
      short8 a1 = *(const short8*)&sA[(w * 32 + 16 + col_lo) * 64 + ks * 32 + quad * 8];
      short8 b[8];
#pragma unroll
      for (int nt = 0; nt < 8; nt++)
        b[nt] = *(const short8*)&sB[(nt * 16 + col_lo) * 64 + ks * 32 + quad * 8];
#pragma unroll
      for (int nt = 0; nt < 8; nt++) {
        acc[0][nt] = __builtin_amdgcn_mfma_f32_16x16x32_bf16(a0, b[nt], acc[0][nt], 0, 0, 0);
        acc[1][nt] = __builtin_amdgcn_mfma_f32_16x16x32_bf16(a1, b[nt], acc[1][nt], 0, 0, 0);
      }
    }
    __syncthreads();
  }

#pragma unroll
  for (int nt = 0; nt < 8; nt++) {
    float bb = bias[nt * 16 + col_lo];
#pragma unroll
    for (int mt = 0; mt < 2; mt++) {
#pragma unroll
      for (int r = 0; r < 4; r++) {
        int rr = row0 + w * 32 + mt * 16 + quad * 4 + r;
        if (rr < n) {
          float v = fmaxf(acc[mt][nt][r] + bb, 0.f);
          out[(size_t)rr * CH + nt * 16 + col_lo] = f2bf(v);
        }
      }
    }
  }
}

// ============================ decoder GEMM via MFMA ============================
__global__ __launch_bounds__(256, 2)
void k_dec(const unsigned short* __restrict__ H, const unsigned short* __restrict__ WTd,
           const float* __restrict__ bd, const float* __restrict__ X,
           const float* __restrict__ alpha_p, float* __restrict__ out, int n) {
  __shared__ unsigned short sA[128 * 64];
  __shared__ unsigned short sB[128 * 64];
  int tid = threadIdx.x;
  int lane = tid & 63;
  int w = tid >> 6;
  int row0 = blockIdx.x * 128;
  int col_lo = lane & 15, quad = lane >> 4;

  f32x4 acc[2][8];
#pragma unroll
  for (int mt = 0; mt < 2; mt++)
#pragma unroll
    for (int nt = 0; nt < 8; nt++) acc[mt][nt] = (f32x4){0.f, 0.f, 0.f, 0.f};

  for (int c = 0; c < 2; c++) {
    int k0 = c * 64;
#pragma unroll
    for (int it = 0; it < 4; it++) {
      int flat = it * 256 + tid;
      int r = flat >> 3;
      int kof = (flat & 7) * 8;
      int gr = row0 + r;
      if (gr > n - 1) gr = n - 1;
      gld16(H + (size_t)gr * CH + k0 + kof, sA + flat * 8);
      gld16(WTd + (size_t)r * CH + k0 + kof, sB + flat * 8);
    }
    __syncthreads();

#pragma unroll
    for (int ks = 0; ks < 2; ks++) {
      short8 a0 = *(const short8*)&sA[(w * 32 + col_lo) * 64 + ks * 32 + quad * 8];
      short8 a1 = *(const short8*)&sA[(w * 32 + 16 + col_lo) * 64 + ks * 32 + quad * 8];
      short8 b[8];
#pragma unroll
      for (int nt = 0; nt < 8; nt++)
        b[nt] = *(const short8*)&sB[(nt * 16 + col_lo) * 64 + ks * 32 + quad * 8];
#pragma unroll
      for (int nt = 0; nt < 8; nt++) {
        acc[0][nt] = __builtin_amdgcn_mfma_f32_16x16x32_bf16(a0, b[nt], acc[0][nt], 0, 0, 0);
        acc[1][nt] = __builtin_amdgcn_mfma_f32_16x16x32_bf16(a1, b[nt], acc[1][nt], 0, 0, 0);
      }
    }
    __syncthreads();
  }

  float al = alpha_p[0];
  float be = 1.f - al;
#pragma unroll
  for (int nt = 0; nt < 8; nt++) {
    float bb = bd[nt * 16 + col_lo];
#pragma unroll
    for (int mt = 0; mt < 2; mt++) {
#pragma unroll
      for (int r = 0; r < 4; r++) {
        int rr = row0 + w * 32 + mt * 16 + quad * 4 + r;
        if (rr < n) {
          int cc = nt * 16 + col_lo;
          float xv = X[(size_t)rr * CH + cc];
          out[(size_t)rr * CH + cc] = al * (acc[mt][nt][r] + bb) + be * xv;
        }
      }
    }
  }
}

// ============================ launch ============================

extern "C" void kernel_launch(void* const* d_in, const int* in_sizes, int n_in,
                              void* d_out, int out_size, void* d_ws, size_t ws_size,
                              hipStream_t stream) {
  const float* x   = (const float*)d_in[0];
  const int*   ei  = (const int*)d_in[1];
  const float* W1l = (const float*)d_in[2];
  const float* b1  = (const float*)d_in[3];
  const float* W1r = (const float*)d_in[4];
  const float* W2l = (const float*)d_in[5];
  const float* b2  = (const float*)d_in[6];
  const float* W2r = (const float*)d_in[7];
  const float* Wd  = (const float*)d_in[8];
  const float* bd  = (const float*)d_in[9];
  const float* alp = (const float*)d_in[10];

  int N = in_sizes[0] / CH;   // 100000
  int E = in_sizes[1] / 2;    // 1600000
  const int* src = ei;
  const int* dst = ei + E;

  char* ws = (char*)d_ws;
  size_t off = 0;
  auto alloc = [&](size_t bytes) -> char* {
    off = (off + 511) & ~size_t(511);
    char* p = ws + off;
    off += bytes;
    return p;
  };
  int*   deg    = (int*)alloc((size_t)N * 4);
  int*   rowptr = (int*)alloc((size_t)(N + 1) * 4);
  int*   ofs    = (int*)alloc((size_t)(NBKT * ABLK + 1) * 4);   // phase-A scanned counts
  int*   bsums  = (int*)alloc(4096);
  int*   sorted = (int*)alloc((size_t)E * 4);
  unsigned short* xb = (unsigned short*)alloc((size_t)N * CH * 2);
  unsigned short* h  = (unsigned short*)alloc((size_t)N * CH * 2);
  unsigned short* WT = (unsigned short*)alloc((size_t)5 * CH * CH * 2);
  // d_out (51.2 MB fp32) double-duty: lower half = bf16 mean scratch; upper half = binned
  // records (6.4 MB, dead before k_agg L1 writes mean). k_dec overwrites d_out fully at the end.
  unsigned short* mean = (unsigned short*)d_out;
  unsigned int* binned = (unsigned int*)((char*)d_out + (size_t)N * CH * 2);

  int chunk = (E + ABLK - 1) / ABLK;   // 5000
  int nA = NBKT * ABLK;                // 62720
  int GA = (nA + 1023) / 1024;         // 62
  int GN = (N + 1023) / 1024;          // 98

  k_cvt<<<(N * CH / 8 + 255) / 256, 256, 0, stream>>>((const float4*)x, (uint4*)xb, N * CH / 8);
  k_wt<<<5, 256, 0, stream>>>(W1l, W1r, W2l, W2r, Wd, WT);

  // --- CSR build: two-phase binning sort, LDS atomics only ---
  k_bhist<<<ABLK, 256, 0, stream>>>(dst, ofs, E, chunk);      // counts into ofs (pre-scan)
  k_scan1<<<GA, 256, 0, stream>>>(ofs, ofs, bsums, nA);       // in-place ok: reads then writes same elems
  k_scan2<<<1, 1024, 0, stream>>>(bsums, GA);
  k_scan3<<<(nA + 255) / 256, 256, 0, stream>>>(ofs, bsums, nA, E);
  k_bin<<<ABLK, 256, 0, stream>>>(src, dst, ofs, binned, E, chunk);
  k_deg<<<NBKT, 256, 0, stream>>>(binned, ofs, deg, N);
  k_scan1<<<GN, 256, 0, stream>>>(deg, rowptr, bsums, N);
  k_scan2<<<1, 1024, 0, stream>>>(bsums, GN);
  k_scan3<<<(N + 255) / 256, 256, 0, stream>>>(rowptr, bsums, N, E);
  k_sort<<<NBKT, 256, 0, stream>>>(binned, ofs, rowptr, sorted, N);

  int gAgg  = (N + 3) / 4;
  int gGemm = (N + 127) / 128;
  unsigned short* WT1l = WT + 0 * CH * CH;
  unsigned short* WT1r = WT + 1 * CH * CH;
  unsigned short* WT2l = WT + 2 * CH * CH;
  unsigned short* WT2r = WT + 3 * CH * CH;
  unsigned short* WTd  = WT + 4 * CH * CH;

  k_agg<<<gAgg, 256, 0, stream>>>(xb, mean, rowptr, sorted, N);
  k_sage<<<gGemm, 256, 0, stream>>>(mean, xb, WT1l, WT1r, b1, h, N);
  k_agg<<<gAgg, 256, 0, stream>>>(h, mean, rowptr, sorted, N);
  k_sage<<<gGemm, 256, 0, stream>>>(mean, h, WT2l, WT2r, b2, h, N);
  k_dec<<<gGemm, 256, 0, stream>>>(h, WTd, bd, x, alp, (float*)d_out, N);
}

// Round 4
// 428.730 us; speedup vs baseline: 5.9374x; 1.0556x over previous
//
#include <hip/hip_runtime.h>
#include <cstddef>
#include <cstdint>

#define CH 128     // IN_CH == HID_CH == 128
#define NBKT 196   // dst >> 9 -> buckets 0..195 (512 nodes each)
#define ABLK 320   // phase-A blocks
#define BKT_NODES 512

typedef __attribute__((ext_vector_type(8))) short short8;
typedef __attribute__((ext_vector_type(4))) float f32x4;

__device__ __forceinline__ unsigned short f2bf(float f) {
  unsigned u = __float_as_uint(f);
  u += 0x7FFF + ((u >> 16) & 1);   // round-to-nearest-even
  return (unsigned short)(u >> 16);
}
__device__ __forceinline__ float bf2f(unsigned int h) {
  return __uint_as_float(h << 16);
}
__device__ __forceinline__ void gld16(const void* g, void* l) {
  __builtin_amdgcn_global_load_lds((const __attribute__((address_space(1))) unsigned int*)g,
                                   (__attribute__((address_space(3))) unsigned int*)l, 16, 0, 0);
}

// ============================ fp32 -> bf16 convert (x) ============================
__global__ void k_cvt(const float4* __restrict__ in, uint4* __restrict__ out, int n8) {
  int i = blockIdx.x * 256 + threadIdx.x;   // 8 elements per thread
  if (i < n8) {
    float4 a = in[i * 2], b = in[i * 2 + 1];
    uint4 o;
    o.x = (unsigned)f2bf(a.x) | ((unsigned)f2bf(a.y) << 16);
    o.y = (unsigned)f2bf(a.z) | ((unsigned)f2bf(a.w) << 16);
    o.z = (unsigned)f2bf(b.x) | ((unsigned)f2bf(b.y) << 16);
    o.w = (unsigned)f2bf(b.z) | ((unsigned)f2bf(b.w) << 16);
    out[i] = o;
  }
}

// ============================ weight transpose + bf16 (5 matrices) ============================
__global__ void k_wt(const float* __restrict__ w0, const float* __restrict__ w1,
                     const float* __restrict__ w2, const float* __restrict__ w3,
                     const float* __restrict__ w4, unsigned short* __restrict__ dst) {
  const float* srcs[5] = {w0, w1, w2, w3, w4};
  const float* w = srcs[blockIdx.x];
  unsigned short* d = dst + (size_t)blockIdx.x * CH * CH;
  for (int idx = threadIdx.x; idx < CH * CH; idx += 256) {
    int k = idx >> 7, nn = idx & 127;
    d[nn * CH + k] = f2bf(w[idx]);
  }
}

// ============================ sort phase A: bin by dst>>9 (no device atomics) ============================
__global__ void k_bhist(const int* __restrict__ dst, int* __restrict__ cnt, int E, int chunk) {
  __shared__ int c[NBKT];
  for (int i = threadIdx.x; i < NBKT; i += 256) c[i] = 0;
  __syncthreads();
  int s = blockIdx.x * chunk;
  int e = min(s + chunk, E);
  for (int i = s + threadIdx.x; i < e; i += 256)
    atomicAdd(&c[dst[i] >> 9], 1);
  __syncthreads();
  for (int i = threadIdx.x; i < NBKT; i += 256)
    cnt[i * ABLK + blockIdx.x] = c[i];
}

// record = src (17b) | dst_local (9b) << 17
__global__ void k_bin(const int* __restrict__ src, const int* __restrict__ dst,
                      const int* __restrict__ ofs, unsigned int* __restrict__ binned,
                      int E, int chunk) {
  __shared__ int cur[NBKT];
  for (int i = threadIdx.x; i < NBKT; i += 256) cur[i] = ofs[i * ABLK + blockIdx.x];
  __syncthreads();
  int s = blockIdx.x * chunk;
  int e = min(s + chunk, E);
  for (int i = s + threadIdx.x; i < e; i += 256) {
    int d = dst[i];
    int b = d >> 9;
    int pos = atomicAdd(&cur[b], 1);   // LDS atomic
    binned[pos] = (unsigned)src[i] | ((unsigned)(d & 511) << 17);
  }
}

// ============================ sort phase B ============================
__global__ void k_deg(const unsigned int* __restrict__ binned, const int* __restrict__ ofs,
                      int* __restrict__ deg, int N) {
  __shared__ int c[BKT_NODES];
  int b = blockIdx.x;
  for (int i = threadIdx.x; i < BKT_NODES; i += 256) c[i] = 0;
  __syncthreads();
  int s = ofs[b * ABLK];
  int e = ofs[(b + 1) * ABLK];
  for (int i = s + threadIdx.x; i < e; i += 256)
    atomicAdd(&c[binned[i] >> 17], 1);
  __syncthreads();
  int base = b * BKT_NODES;
  for (int i = threadIdx.x; i < BKT_NODES; i += 256)
    if (base + i < N) deg[base + i] = c[i];
}

__global__ void k_sort(const unsigned int* __restrict__ binned, const int* __restrict__ ofs,
                       const int* __restrict__ rowptr, int* __restrict__ sorted, int N) {
  __shared__ int cur[BKT_NODES];
  int b = blockIdx.x;
  int base = b * BKT_NODES;
  for (int i = threadIdx.x; i < BKT_NODES; i += 256)
    cur[i] = (base + i < N) ? rowptr[base + i] : 0;
  __syncthreads();
  int s = ofs[b * ABLK];
  int e = ofs[(b + 1) * ABLK];
  for (int i = s + threadIdx.x; i < e; i += 256) {
    unsigned w = binned[i];
    int dl = w >> 17;
    int pos = atomicAdd(&cur[dl], 1);   // LDS atomic
    sorted[pos] = w & 0x1FFFF;
  }
}

// ============================ generic scan chain (1024 elems/block) ============================
__global__ void k_scan1(const int* __restrict__ deg, int* __restrict__ rowptr,
                        int* __restrict__ bsums, int n) {
  __shared__ int sh[256];
  int tid = threadIdx.x;
  int base = blockIdx.x * 1024 + tid * 4;
  int v0 = (base + 0 < n) ? deg[base + 0] : 0;
  int v1 = (base + 1 < n) ? deg[base + 1] : 0;
  int v2 = (base + 2 < n) ? deg[base + 2] : 0;
  int v3 = (base + 3 < n) ? deg[base + 3] : 0;
  int tot = v0 + v1 + v2 + v3;
  sh[tid] = tot;
  __syncthreads();
  for (int off = 1; off < 256; off <<= 1) {
    int y = (tid >= off) ? sh[tid - off] : 0;
    __syncthreads();
    sh[tid] += y;
    __syncthreads();
  }
  int excl = sh[tid] - tot;
  if (base + 0 < n) rowptr[base + 0] = excl;
  if (base + 1 < n) rowptr[base + 1] = excl + v0;
  if (base + 2 < n) rowptr[base + 2] = excl + v0 + v1;
  if (base + 3 < n) rowptr[base + 3] = excl + v0 + v1 + v2;
  if (tid == 255) bsums[blockIdx.x] = sh[255];
}

__global__ void k_scan2(int* __restrict__ bsums, int g) {
  __shared__ int sh[1024];
  int tid = threadIdx.x;
  int v = (tid < g) ? bsums[tid] : 0;
  sh[tid] = v;
  __syncthreads();
  for (int off = 1; off < 1024; off <<= 1) {
    int y = (tid >= off) ? sh[tid - off] : 0;
    __syncthreads();
    sh[tid] += y;
    __syncthreads();
  }
  if (tid < g) bsums[tid] = sh[tid] - v;
}

__global__ void k_scan3(int* __restrict__ arr, const int* __restrict__ bsums, int n, int total) {
  int i = blockIdx.x * 256 + threadIdx.x;
  if (i < n) arr[i] += bsums[i >> 10];
  if (i == 0) arr[n] = total;
}

// ============================ mean aggregation v2 ============================
// Persistent waves: wave grid-strides over nodes (~12 nodes/wave averages out the
// Poisson(16) degree imbalance). 8-deep load pipeline; masked tail block (value-
// predicated, address clamped to beg). Lane = 2 channels; 32-bit offset addressing.
__global__ __launch_bounds__(256)
void k_agg(const unsigned int* __restrict__ in, unsigned int* __restrict__ out,
           const int* __restrict__ rowptr, const int* __restrict__ sorted_src,
           int n, int nwaves) {
  int wid = (blockIdx.x * 256 + threadIdx.x) >> 6;
  int lane = threadIdx.x & 63;

  for (int node = wid; node < n; node += nwaves) {
    int beg = rowptr[node], end = rowptr[node + 1];
    float ax = 0.f, ay = 0.f;
    int e = beg;
    for (; e + 8 <= end; e += 8) {
      unsigned int v[8];
#pragma unroll
      for (int j = 0; j < 8; j++)
        v[j] = in[((unsigned)sorted_src[e + j] << 6) + lane];
#pragma unroll
      for (int j = 0; j < 8; j++) {
        ax += bf2f(v[j] & 0xffff);
        ay += bf2f(v[j] >> 16);
      }
    }
    if (e < end) {
      unsigned int v[8];
#pragma unroll
      for (int j = 0; j < 8; j++) {
        int idx = (e + j < end) ? (e + j) : beg;   // clamp: redundant load of row[beg], L1-hot
        v[j] = in[((unsigned)sorted_src[idx] << 6) + lane];
      }
#pragma unroll
      for (int j = 0; j < 8; j++) {
        float lo = (e + j < end) ? bf2f(v[j] & 0xffff) : 0.f;
        float hi = (e + j < end) ? bf2f(v[j] >> 16) : 0.f;
        ax += lo;
        ay += hi;
      }
    }
    int d = end - beg;
    float inv = (d > 0) ? (1.f / (float)d) : 0.f;
    out[((unsigned)node << 6) + lane] =
        (unsigned)f2bf(ax * inv) | ((unsigned)f2bf(ay * inv) << 16);
  }
}

// ============================ fused SAGE dual-GEMM via MFMA bf16 ============================
__global__ __launch_bounds__(256, 2)
void k_sage(const unsigned short* __restrict__ Am, const unsigned short* __restrict__ Ax,
            const unsigned short* __restrict__ WTl, const unsigned short* __restrict__ WTr,
            const float* __restrict__ bias, unsigned short* __restrict__ out, int n) {
  __shared__ unsigned short sA[128 * 64];
  __shared__ unsigned short sB[128 * 64];
  int tid = threadIdx.x;
  int lane = tid & 63;
  int w = tid >> 6;
  int row0 = blockIdx.x * 128;
  int col_lo = lane & 15, quad = lane >> 4;

  f32x4 acc[2][8];
#pragma unroll
  for (int mt = 0; mt < 2; mt++)
#pragma unroll
    for (int nt = 0; nt < 8; nt++) acc[mt][nt] = (f32x4){0.f, 0.f, 0.f, 0.f};

  const unsigned short* As[4] = {Am, Am, Ax, Ax};
  const unsigned short* Bs[4] = {WTl, WTl, WTr, WTr};
  const int k0s[4] = {0, 64, 0, 64};

  for (int c = 0; c < 4; c++) {
    const unsigned short* Ap = As[c];
    const unsigned short* Bp = Bs[c];
    int k0 = k0s[c];
#pragma unroll
    for (int it = 0; it < 4; it++) {
      int flat = it * 256 + tid;
      int r = flat >> 3;
      int kof = (flat & 7) * 8;
      int gr = row0 + r;
      if (gr > n - 1) gr = n - 1;
      gld16(Ap + (size_t)gr * CH + k0 + kof, sA + flat * 8);
      gld16(Bp + (size_t)r * CH + k0 + kof, sB + flat * 8);
    }
    __syncthreads();

#pragma unroll
    for (int ks = 0; ks < 2; ks++) {
      short8 a0 = *(const short8*)&sA[(w * 32 + col_lo) * 64 + ks * 32 + quad * 8];
      short8 a1 = *(const short8*)&sA[(w * 32 + 16 + col_lo) * 64 + ks * 32 + quad * 8];
      short8 b[8];
#pragma unroll
      for (int nt = 0; nt < 8; nt++)
        b[nt] = *(const short8*)&sB[(nt * 16 + col_lo) * 64 + ks * 32 + quad * 8];
#pragma unroll
      for (int nt = 0; nt < 8; nt++) {
        acc[0][nt] = __builtin_amdgcn_mfma_f32_16x16x32_bf16(a0, b[nt], acc[0][nt], 0, 0, 0);
        acc[1][nt] = __builtin_amdgcn_mfma_f32_16x16x32_bf16(a1, b[nt], acc[1][nt], 0, 0, 0);
      }
    }
    __syncthreads();
  }

#pragma unroll
  for (int nt = 0; nt < 8; nt++) {
    float bb = bias[nt * 16 + col_lo];
#pragma unroll
    for (int mt = 0; mt < 2; mt++) {
#pragma unroll
      for (int r = 0; r < 4; r++) {
        int rr = row0 + w * 32 + mt * 16 + quad * 4 + r;
        if (rr < n) {
          float v = fmaxf(acc[mt][nt][r] + bb, 0.f);
          out[(size_t)rr * CH + nt * 16 + col_lo] = f2bf(v);
        }
      }
    }
  }
}

// ============================ decoder GEMM via MFMA ============================
__global__ __launch_bounds__(256, 2)
void k_dec(const unsigned short* __restrict__ H, const unsigned short* __restrict__ WTd,
           const float* __restrict__ bd, const float* __restrict__ X,
           const float* __restrict__ alpha_p, float* __restrict__ out, int n) {
  __shared__ unsigned short sA[128 * 64];
  __shared__ unsigned short sB[128 * 64];
  int tid = threadIdx.x;
  int lane = tid & 63;
  int w = tid >> 6;
  int row0 = blockIdx.x * 128;
  int col_lo = lane & 15, quad = lane >> 4;

  f32x4 acc[2][8];
#pragma unroll
  for (int mt = 0; mt < 2; mt++)
#pragma unroll
    for (int nt = 0; nt < 8; nt++) acc[mt][nt] = (f32x4){0.f, 0.f, 0.f, 0.f};

  for (int c = 0; c < 2; c++) {
    int k0 = c * 64;
#pragma unroll
    for (int it = 0; it < 4; it++) {
      int flat = it * 256 + tid;
      int r = flat >> 3;
      int kof = (flat & 7) * 8;
      int gr = row0 + r;
      if (gr > n - 1) gr = n - 1;
      gld16(H + (size_t)gr * CH + k0 + kof, sA + flat * 8);
      gld16(WTd + (size_t)r * CH + k0 + kof, sB + flat * 8);
    }
    __syncthreads();

#pragma unroll
    for (int ks = 0; ks < 2; ks++) {
      short8 a0 = *(const short8*)&sA[(w * 32 + col_lo) * 64 + ks * 32 + quad * 8];
      short8 a1 = *(const short8*)&sA[(w * 32 + 16 + col_lo) * 64 + ks * 32 + quad * 8];
      short8 b[8];
#pragma unroll
      for (int nt = 0; nt < 8; nt++)
        b[nt] = *(const short8*)&sB[(nt * 16 + col_lo) * 64 + ks * 32 + quad * 8];
#pragma unroll
      for (int nt = 0; nt < 8; nt++) {
        acc[0][nt] = __builtin_amdgcn_mfma_f32_16x16x32_bf16(a0, b[nt], acc[0][nt], 0, 0, 0);
        acc[1][nt] = __builtin_amdgcn_mfma_f32_16x16x32_bf16(a1, b[nt], acc[1][nt], 0, 0, 0);
      }
    }
    __syncthreads();
  }

  float al = alpha_p[0];
  float be = 1.f - al;
#pragma unroll
  for (int nt = 0; nt < 8; nt++) {
    float bb = bd[nt * 16 + col_lo];
#pragma unroll
    for (int mt = 0; mt < 2; mt++) {
#pragma unroll
      for (int r = 0; r < 4; r++) {
        int rr = row0 + w * 32 + mt * 16 + quad * 4 + r;
        if (rr < n) {
          int cc = nt * 16 + col_lo;
          float xv = X[(size_t)rr * CH + cc];
          out[(size_t)rr * CH + cc] = al * (acc[mt][nt][r] + bb) + be * xv;
        }
      }
    }
  }
}

// ============================ launch ============================

extern "C" void kernel_launch(void* const* d_in, const int* in_sizes, int n_in,
                              void* d_out, int out_size, void* d_ws, size_t ws_size,
                              hipStream_t stream) {
  const float* x   = (const float*)d_in[0];
  const int*   ei  = (const int*)d_in[1];
  const float* W1l = (const float*)d_in[2];
  const float* b1  = (const float*)d_in[3];
  const float* W1r = (const float*)d_in[4];
  const float* W2l = (const float*)d_in[5];
  const float* b2  = (const float*)d_in[6];
  const float* W2r = (const float*)d_in[7];
  const float* Wd  = (const float*)d_in[8];
  const float* bd  = (const float*)d_in[9];
  const float* alp = (const float*)d_in[10];

  int N = in_sizes[0] / CH;   // 100000
  int E = in_sizes[1] / 2;    // 1600000
  const int* src = ei;
  const int* dst = ei + E;

  char* ws = (char*)d_ws;
  size_t off = 0;
  auto alloc = [&](size_t bytes) -> char* {
    off = (off + 511) & ~size_t(511);
    char* p = ws + off;
    off += bytes;
    return p;
  };
  int*   deg    = (int*)alloc((size_t)N * 4);
  int*   rowptr = (int*)alloc((size_t)(N + 1) * 4);
  int*   ofs    = (int*)alloc((size_t)(NBKT * ABLK + 1) * 4);
  int*   bsums  = (int*)alloc(4096);
  int*   sorted = (int*)alloc((size_t)E * 4);
  unsigned short* xb = (unsigned short*)alloc((size_t)N * CH * 2);
  unsigned short* h  = (unsigned short*)alloc((size_t)N * CH * 2);
  unsigned short* WT = (unsigned short*)alloc((size_t)5 * CH * CH * 2);
  unsigned short* mean = (unsigned short*)d_out;
  unsigned int* binned = (unsigned int*)((char*)d_out + (size_t)N * CH * 2);

  int chunk = (E + ABLK - 1) / ABLK;   // 5000
  int nA = NBKT * ABLK;                // 62720
  int GA = (nA + 1023) / 1024;         // 62
  int GN = (N + 1023) / 1024;          // 98

  k_cvt<<<(N * CH / 8 + 255) / 256, 256, 0, stream>>>((const float4*)x, (uint4*)xb, N * CH / 8);
  k_wt<<<5, 256, 0, stream>>>(W1l, W1r, W2l, W2r, Wd, WT);

  // --- CSR build: two-phase binning sort, LDS atomics only ---
  k_bhist<<<ABLK, 256, 0, stream>>>(dst, ofs, E, chunk);
  k_scan1<<<GA, 256, 0, stream>>>(ofs, ofs, bsums, nA);
  k_scan2<<<1, 1024, 0, stream>>>(bsums, GA);
  k_scan3<<<(nA + 255) / 256, 256, 0, stream>>>(ofs, bsums, nA, E);
  k_bin<<<ABLK, 256, 0, stream>>>(src, dst, ofs, binned, E, chunk);
  k_deg<<<NBKT, 256, 0, stream>>>(binned, ofs, deg, N);
  k_scan1<<<GN, 256, 0, stream>>>(deg, rowptr, bsums, N);
  k_scan2<<<1, 1024, 0, stream>>>(bsums, GN);
  k_scan3<<<(N + 255) / 256, 256, 0, stream>>>(rowptr, bsums, N, E);
  k_sort<<<NBKT, 256, 0, stream>>>(binned, ofs, rowptr, sorted, N);

  int gAggBlocks = 2048;               // 8192 waves, ~12 nodes/wave
  int nWaves = gAggBlocks * 4;
  int gGemm = (N + 127) / 128;
  unsigned short* WT1l = WT + 0 * CH * CH;
  unsigned short* WT1r = WT + 1 * CH * CH;
  unsigned short* WT2l = WT + 2 * CH * CH;
  unsigned short* WT2r = WT + 3 * CH * CH;
  unsigned short* WTd  = WT + 4 * CH * CH;

  k_agg<<<gAggBlocks, 256, 0, stream>>>((const unsigned int*)xb, (unsigned int*)mean,
                                        rowptr, sorted, N, nWaves);
  k_sage<<<gGemm, 256, 0, stream>>>(mean, xb, WT1l, WT1r, b1, h, N);
  k_agg<<<gAggBlocks, 256, 0, stream>>>((const unsigned int*)h, (unsigned int*)mean,
                                        rowptr, sorted, N, nWaves);
  k_sage<<<gGemm, 256, 0, stream>>>(mean, h, WT2l, WT2r, b2, h, N);
  k_dec<<<gGemm, 256, 0, stream>>>(h, WTd, bd, x, alp, (float*)d_out, N);
}

// Round 5
// 421.268 us; speedup vs baseline: 6.0426x; 1.0177x over previous
//
#include <hip/hip_runtime.h>
#include <cstddef>
#include <cstdint>

#define CH 128     // IN_CH == HID_CH == 128
#define NBKT 196   // dst >> 9 -> buckets 0..195 (512 nodes each)
#define ABLK 320   // phase-A blocks
#define BKT_NODES 512

typedef __attribute__((ext_vector_type(8))) short short8;
typedef __attribute__((ext_vector_type(4))) float f32x4;

__device__ __forceinline__ unsigned short f2bf(float f) {
  unsigned u = __float_as_uint(f);
  u += 0x7FFF + ((u >> 16) & 1);   // round-to-nearest-even
  return (unsigned short)(u >> 16);
}
__device__ __forceinline__ float bf_lo(unsigned int u) {   // low bf16 of packed pair
  return __uint_as_float(u << 16);
}
__device__ __forceinline__ float bf_hi(unsigned int u) {   // high bf16 of packed pair
  return __uint_as_float(u & 0xffff0000u);
}
__device__ __forceinline__ void gld16(const void* g, void* l) {
  __builtin_amdgcn_global_load_lds((const __attribute__((address_space(1))) unsigned int*)g,
                                   (__attribute__((address_space(3))) unsigned int*)l, 16, 0, 0);
}

// ============================ fp32 -> bf16 convert (x) ============================
__global__ void k_cvt(const float4* __restrict__ in, uint4* __restrict__ out, int n8) {
  int i = blockIdx.x * 256 + threadIdx.x;   // 8 elements per thread
  if (i < n8) {
    float4 a = in[i * 2], b = in[i * 2 + 1];
    uint4 o;
    o.x = (unsigned)f2bf(a.x) | ((unsigned)f2bf(a.y) << 16);
    o.y = (unsigned)f2bf(a.z) | ((unsigned)f2bf(a.w) << 16);
    o.z = (unsigned)f2bf(b.x) | ((unsigned)f2bf(b.y) << 16);
    o.w = (unsigned)f2bf(b.z) | ((unsigned)f2bf(b.w) << 16);
    out[i] = o;
  }
}

// ============================ weight transpose + bf16 (5 matrices) ============================
__global__ void k_wt(const float* __restrict__ w0, const float* __restrict__ w1,
                     const float* __restrict__ w2, const float* __restrict__ w3,
                     const float* __restrict__ w4, unsigned short* __restrict__ dst) {
  const float* srcs[5] = {w0, w1, w2, w3, w4};
  const float* w = srcs[blockIdx.x];
  unsigned short* d = dst + (size_t)blockIdx.x * CH * CH;
  for (int idx = threadIdx.x; idx < CH * CH; idx += 256) {
    int k = idx >> 7, nn = idx & 127;
    d[nn * CH + k] = f2bf(w[idx]);
  }
}

// ============================ sort phase A: bin by dst>>9 (no device atomics) ============================
__global__ void k_bhist(const int* __restrict__ dst, int* __restrict__ cnt, int E, int chunk) {
  __shared__ int c[NBKT];
  for (int i = threadIdx.x; i < NBKT; i += 256) c[i] = 0;
  __syncthreads();
  int s = blockIdx.x * chunk;
  int e = min(s + chunk, E);
  for (int i = s + threadIdx.x; i < e; i += 256)
    atomicAdd(&c[dst[i] >> 9], 1);
  __syncthreads();
  for (int i = threadIdx.x; i < NBKT; i += 256)
    cnt[i * ABLK + blockIdx.x] = c[i];
}

// record = src (17b) | dst_local (9b) << 17
__global__ void k_bin(const int* __restrict__ src, const int* __restrict__ dst,
                      const int* __restrict__ ofs, unsigned int* __restrict__ binned,
                      int E, int chunk) {
  __shared__ int cur[NBKT];
  for (int i = threadIdx.x; i < NBKT; i += 256) cur[i] = ofs[i * ABLK + blockIdx.x];
  __syncthreads();
  int s = blockIdx.x * chunk;
  int e = min(s + chunk, E);
  for (int i = s + threadIdx.x; i < e; i += 256) {
    int d = dst[i];
    int b = d >> 9;
    int pos = atomicAdd(&cur[b], 1);   // LDS atomic
    binned[pos] = (unsigned)src[i] | ((unsigned)(d & 511) << 17);
  }
}

// ============================ sort phase B: fused hist + scan + rowptr + scatter ============================
// One block per bucket. rowptr[node] = bucket_edge_start + exclusive_scan(bucket histogram),
// so the global N-scan chain (k_deg + 3 scan kernels + k_sort) collapses into this one kernel.
__global__ __launch_bounds__(256)
void k_bucket(const unsigned int* __restrict__ binned, const int* __restrict__ ofs,
              int* __restrict__ rowptr, int* __restrict__ sorted, int N, int E, int nbkt) {
  __shared__ int c[BKT_NODES];
  __shared__ int tsum[256];
  __shared__ int cur[BKT_NODES];
  int b = blockIdx.x, t = threadIdx.x;
  int s = ofs[b * ABLK];
  int e = ofs[(b + 1) * ABLK];   // last bucket: ofs[NBKT*ABLK] == E
  c[t] = 0; c[t + 256] = 0;
  __syncthreads();
  for (int i = s + t; i < e; i += 256)
    atomicAdd(&c[binned[i] >> 17], 1);
  __syncthreads();
  int v0 = c[2 * t], v1 = c[2 * t + 1];
  int tot = v0 + v1;
  tsum[t] = tot;
  __syncthreads();
  for (int o = 1; o < 256; o <<= 1) {
    int y = (t >= o) ? tsum[t - o] : 0;
    __syncthreads();
    tsum[t] += y;
    __syncthreads();
  }
  int excl = tsum[t] - tot;
  int base = b * BKT_NODES;
  int r0 = s + excl, r1 = s + excl + v0;
  if (base + 2 * t < N)     rowptr[base + 2 * t]     = r0;
  if (base + 2 * t + 1 < N) rowptr[base + 2 * t + 1] = r1;
  cur[2 * t] = r0; cur[2 * t + 1] = r1;
  __syncthreads();
  for (int i = s + t; i < e; i += 256) {
    unsigned w = binned[i];
    int pos = atomicAdd(&cur[w >> 17], 1);   // LDS atomic
    sorted[pos] = w & 0x1FFFF;
  }
  if (b == nbkt - 1 && t == 0) rowptr[N] = E;
}

// ============================ scan chain for ofs (1024 elems/block) ============================
__global__ void k_scan1(const int* __restrict__ deg, int* __restrict__ rowptr,
                        int* __restrict__ bsums, int n) {
  __shared__ int sh[256];
  int tid = threadIdx.x;
  int base = blockIdx.x * 1024 + tid * 4;
  int v0 = (base + 0 < n) ? deg[base + 0] : 0;
  int v1 = (base + 1 < n) ? deg[base + 1] : 0;
  int v2 = (base + 2 < n) ? deg[base + 2] : 0;
  int v3 = (base + 3 < n) ? deg[base + 3] : 0;
  int tot = v0 + v1 + v2 + v3;
  sh[tid] = tot;
  __syncthreads();
  for (int off = 1; off < 256; off <<= 1) {
    int y = (tid >= off) ? sh[tid - off] : 0;
    __syncthreads();
    sh[tid] += y;
    __syncthreads();
  }
  int excl = sh[tid] - tot;
  if (base + 0 < n) rowptr[base + 0] = excl;
  if (base + 1 < n) rowptr[base + 1] = excl + v0;
  if (base + 2 < n) rowptr[base + 2] = excl + v0 + v1;
  if (base + 3 < n) rowptr[base + 3] = excl + v0 + v1 + v2;
  if (tid == 255) bsums[blockIdx.x] = sh[255];
}

__global__ void k_scan2(int* __restrict__ bsums, int g) {
  __shared__ int sh[1024];
  int tid = threadIdx.x;
  int v = (tid < g) ? bsums[tid] : 0;
  sh[tid] = v;
  __syncthreads();
  for (int off = 1; off < 1024; off <<= 1) {
    int y = (tid >= off) ? sh[tid - off] : 0;
    __syncthreads();
    sh[tid] += y;
    __syncthreads();
  }
  if (tid < g) bsums[tid] = sh[tid] - v;
}

__global__ void k_scan3(int* __restrict__ arr, const int* __restrict__ bsums, int n, int total) {
  int i = blockIdx.x * 256 + threadIdx.x;
  if (i < n) arr[i] += bsums[i >> 10];
  if (i == 0) arr[n] = total;
}

// ============================ mean aggregation v3 ============================
// Persistent waves; 2 edges per memory instruction: lane holds uint2 (4 channels),
// 32 lanes cover a 128-ch row, half-waves process edges e+0 / e+1 simultaneously
// (512 B per load inst). Cross-half combine via 4 shuffles once per node.
__global__ __launch_bounds__(256)
void k_agg(const uint2* __restrict__ in2, uint2* __restrict__ out2,
           const int* __restrict__ rowptr, const int* __restrict__ sorted_src,
           int n, int nwaves) {
  int wid = (blockIdx.x * 256 + threadIdx.x) >> 6;
  int lane = threadIdx.x & 63;
  int half = lane >> 5;        // 0: even edges, 1: odd edges
  int sl = lane & 31;          // uint2 index within row

  for (int node = wid; node < n; node += nwaves) {
    int beg = rowptr[node], end = rowptr[node + 1];
    float a0 = 0.f, a1 = 0.f, a2 = 0.f, a3 = 0.f;
    int e = beg;
    for (; e + 8 <= end; e += 8) {       // 4 pair-iterations = 8 edges
      uint2 v[4];
#pragma unroll
      for (int j = 0; j < 4; j++)
        v[j] = in2[((unsigned)sorted_src[e + 2 * j + half] << 5) + sl];
#pragma unroll
      for (int j = 0; j < 4; j++) {
        a0 += bf_lo(v[j].x); a1 += bf_hi(v[j].x);
        a2 += bf_lo(v[j].y); a3 += bf_hi(v[j].y);
      }
    }
    if (e < end) {                        // masked tail block (value-predicated)
      uint2 v[4];
#pragma unroll
      for (int j = 0; j < 4; j++) {
        int k = e + 2 * j + half;
        int idx = (k < end) ? k : beg;    // clamped loads hit L1 (row[beg] hot)
        uint2 tv = in2[((unsigned)sorted_src[idx] << 5) + sl];
        if (k >= end) { tv.x = 0u; tv.y = 0u; }
        v[j] = tv;
      }
#pragma unroll
      for (int j = 0; j < 4; j++) {
        a0 += bf_lo(v[j].x); a1 += bf_hi(v[j].x);
        a2 += bf_lo(v[j].y); a3 += bf_hi(v[j].y);
      }
    }
    // combine even-edge (lanes 0-31) and odd-edge (lanes 32-63) partials
    a0 += __shfl(a0, lane ^ 32);
    a1 += __shfl(a1, lane ^ 32);
    a2 += __shfl(a2, lane ^ 32);
    a3 += __shfl(a3, lane ^ 32);
    int d = end - beg;
    float inv = (d > 0) ? (1.f / (float)d) : 0.f;
    if (half == 0) {
      uint2 o;
      o.x = (unsigned)f2bf(a0 * inv) | ((unsigned)f2bf(a1 * inv) << 16);
      o.y = (unsigned)f2bf(a2 * inv) | ((unsigned)f2bf(a3 * inv) << 16);
      out2[((unsigned)node << 5) + sl] = o;
    }
  }
}

// ============================ fused SAGE dual-GEMM via MFMA bf16 ============================
__global__ __launch_bounds__(256, 2)
void k_sage(const unsigned short* __restrict__ Am, const unsigned short* __restrict__ Ax,
            const unsigned short* __restrict__ WTl, const unsigned short* __restrict__ WTr,
            const float* __restrict__ bias, unsigned short* __restrict__ out, int n) {
  __shared__ unsigned short sA[128 * 64];
  __shared__ unsigned short sB[128 * 64];
  int tid = threadIdx.x;
  int lane = tid & 63;
  int w = tid >> 6;
  int row0 = blockIdx.x * 128;
  int col_lo = lane & 15, quad = lane >> 4;

  f32x4 acc[2][8];
#pragma unroll
  for (int mt = 0; mt < 2; mt++)
#pragma unroll
    for (int nt = 0; nt < 8; nt++) acc[mt][nt] = (f32x4){0.f, 0.f, 0.f, 0.f};

  const unsigned short* As[4] = {Am, Am, Ax, Ax};
  const unsigned short* Bs[4] = {WTl, WTl, WTr, WTr};
  const int k0s[4] = {0, 64, 0, 64};

  for (int c = 0; c < 4; c++) {
    const unsigned short* Ap = As[c];
    const unsigned short* Bp = Bs[c];
    int k0 = k0s[c];
#pragma unroll
    for (int it = 0; it < 4; it++) {
      int flat = it * 256 + tid;
      int r = flat >> 3;
      int kof = (flat & 7) * 8;
      int gr = row0 + r;
      if (gr > n - 1) gr = n - 1;
      gld16(Ap + (size_t)gr * CH + k0 + kof, sA + flat * 8);
      gld16(Bp + (size_t)r * CH + k0 + kof, sB + flat * 8);
    }
    __syncthreads();

#pragma unroll
    for (int ks = 0; ks < 2; ks++) {
      short8 a0 = *(const short8*)&sA[(w * 32 + col_lo) * 64 + ks * 32 + quad * 8];
      short8 a1 = *(const short8*)&sA[(w * 32 + 16 + col_lo) * 64 + ks * 32 + quad * 8];
      short8 b[8];
#pragma unroll
      for (int nt = 0; nt < 8; nt++)
        b[nt] = *(const short8*)&sB[(nt * 16 + col_lo) * 64 + ks * 32 + quad * 8];
#pragma unroll
      for (int nt = 0; nt < 8; nt++) {
        acc[0][nt] = __builtin_amdgcn_mfma_f32_16x16x32_bf16(a0, b[nt], acc[0][nt], 0, 0, 0);
        acc[1][nt] = __builtin_amdgcn_mfma_f32_16x16x32_bf16(a1, b[nt], acc[1][nt], 0, 0, 0);
      }
    }
    __syncthreads();
  }

#pragma unroll
  for (int nt = 0; nt < 8; nt++) {
    float bb = bias[nt * 16 + col_lo];
#pragma unroll
    for (int mt = 0; mt < 2; mt++) {
#pragma unroll
      for (int r = 0; r < 4; r++) {
        int rr = row0 + w * 32 + mt * 16 + quad * 4 + r;
        if (rr < n) {
          float v = fmaxf(acc[mt][nt][r] + bb, 0.f);
          out[(size_t)rr * CH + nt * 16 + col_lo] = f2bf(v);
        }
      }
    }
  }
}

// ============================ decoder GEMM via MFMA ============================
__global__ __launch_bounds__(256, 2)
void k_dec(const unsigned short* __restrict__ H, const unsigned short* __restrict__ WTd,
           const float* __restrict__ bd, const float* __restrict__ X,
           const float* __restrict__ alpha_p, float* __restrict__ out, int n) {
  __shared__ unsigned short sA[128 * 64];
  __shared__ unsigned short sB[128 * 64];
  int tid = threadIdx.x;
  int lane = tid & 63;
  int w = tid >> 6;
  int row0 = blockIdx.x * 128;
  int col_lo = lane & 15, quad = lane >> 4;

  f32x4 acc[2][8];
#pragma unroll
  for (int mt = 0; mt < 2; mt++)
#pragma unroll
    for (int nt = 0; nt < 8; nt++) acc[mt][nt] = (f32x4){0.f, 0.f, 0.f, 0.f};

  for (int c = 0; c < 2; c++) {
    int k0 = c * 64;
#pragma unroll
    for (int it = 0; it < 4; it++) {
      int flat = it * 256 + tid;
      int r = flat >> 3;
      int kof = (flat & 7) * 8;
      int gr = row0 + r;
      if (gr > n - 1) gr = n - 1;
      gld16(H + (size_t)gr * CH + k0 + kof, sA + flat * 8);
      gld16(WTd + (size_t)r * CH + k0 + kof, sB + flat * 8);
    }
    __syncthreads();

#pragma unroll
    for (int ks = 0; ks < 2; ks++) {
      short8 a0 = *(const short8*)&sA[(w * 32 + col_lo) * 64 + ks * 32 + quad * 8];
      short8 a1 = *(const short8*)&sA[(w * 32 + 16 + col_lo) * 64 + ks * 32 + quad * 8];
      short8 b[8];
#pragma unroll
      for (int nt = 0; nt < 8; nt++)
        b[nt] = *(const short8*)&sB[(nt * 16 + col_lo) * 64 + ks * 32 + quad * 8];
#pragma unroll
      for (int nt = 0; nt < 8; nt++) {
        acc[0][nt] = __builtin_amdgcn_mfma_f32_16x16x32_bf16(a0, b[nt], acc[0][nt], 0, 0, 0);
        acc[1][nt] = __builtin_amdgcn_mfma_f32_16x16x32_bf16(a1, b[nt], acc[1][nt], 0, 0, 0);
      }
    }
    __syncthreads();
  }

  float al = alpha_p[0];
  float be = 1.f - al;
#pragma unroll
  for (int nt = 0; nt < 8; nt++) {
    float bb = bd[nt * 16 + col_lo];
#pragma unroll
    for (int mt = 0; mt < 2; mt++) {
#pragma unroll
      for (int r = 0; r < 4; r++) {
        int rr = row0 + w * 32 + mt * 16 + quad * 4 + r;
        if (rr < n) {
          int cc = nt * 16 + col_lo;
          float xv = X[(size_t)rr * CH + cc];
          out[(size_t)rr * CH + cc] = al * (acc[mt][nt][r] + bb) + be * xv;
        }
      }
    }
  }
}

// ============================ launch ============================

extern "C" void kernel_launch(void* const* d_in, const int* in_sizes, int n_in,
                              void* d_out, int out_size, void* d_ws, size_t ws_size,
                              hipStream_t stream) {
  const float* x   = (const float*)d_in[0];
  const int*   ei  = (const int*)d_in[1];
  const float* W1l = (const float*)d_in[2];
  const float* b1  = (const float*)d_in[3];
  const float* W1r = (const float*)d_in[4];
  const float* W2l = (const float*)d_in[5];
  const float* b2  = (const float*)d_in[6];
  const float* W2r = (const float*)d_in[7];
  const float* Wd  = (const float*)d_in[8];
  const float* bd  = (const float*)d_in[9];
  const float* alp = (const float*)d_in[10];

  int N = in_sizes[0] / CH;   // 100000
  int E = in_sizes[1] / 2;    // 1600000
  const int* src = ei;
  const int* dst = ei + E;

  char* ws = (char*)d_ws;
  size_t off = 0;
  auto alloc = [&](size_t bytes) -> char* {
    off = (off + 511) & ~size_t(511);
    char* p = ws + off;
    off += bytes;
    return p;
  };
  int*   rowptr = (int*)alloc((size_t)(N + 1) * 4);
  int*   ofs    = (int*)alloc((size_t)(NBKT * ABLK + 1) * 4);
  int*   bsums  = (int*)alloc(4096);
  int*   sorted = (int*)alloc((size_t)E * 4);
  unsigned short* xb = (unsigned short*)alloc((size_t)N * CH * 2);
  unsigned short* h  = (unsigned short*)alloc((size_t)N * CH * 2);
  unsigned short* WT = (unsigned short*)alloc((size_t)5 * CH * CH * 2);
  unsigned short* mean = (unsigned short*)d_out;
  unsigned int* binned = (unsigned int*)((char*)d_out + (size_t)N * CH * 2);

  int chunk = (E + ABLK - 1) / ABLK;   // 5000
  int nA = NBKT * ABLK;                // 62720
  int GA = (nA + 1023) / 1024;         // 62

  k_cvt<<<(N * CH / 8 + 255) / 256, 256, 0, stream>>>((const float4*)x, (uint4*)xb, N * CH / 8);
  k_wt<<<5, 256, 0, stream>>>(W1l, W1r, W2l, W2r, Wd, WT);

  // --- CSR build: two-phase binning sort, LDS atomics only ---
  k_bhist<<<ABLK, 256, 0, stream>>>(dst, ofs, E, chunk);
  k_scan1<<<GA, 256, 0, stream>>>(ofs, ofs, bsums, nA);
  k_scan2<<<1, 1024, 0, stream>>>(bsums, GA);
  k_scan3<<<(nA + 255) / 256, 256, 0, stream>>>(ofs, bsums, nA, E);
  k_bin<<<ABLK, 256, 0, stream>>>(src, dst, ofs, binned, E, chunk);
  k_bucket<<<NBKT, 256, 0, stream>>>(binned, ofs, rowptr, sorted, N, E, NBKT);

  int gAggBlocks = 2048;               // 8192 waves, ~12 nodes/wave
  int nWaves = gAggBlocks * 4;
  int gGemm = (N + 127) / 128;
  unsigned short* WT1l = WT + 0 * CH * CH;
  unsigned short* WT1r = WT + 1 * CH * CH;
  unsigned short* WT2l = WT + 2 * CH * CH;
  unsigned short* WT2r = WT + 3 * CH * CH;
  unsigned short* WTd  = WT + 4 * CH * CH;

  k_agg<<<gAggBlocks, 256, 0, stream>>>((const uint2*)xb, (uint2*)mean, rowptr, sorted, N, nWaves);
  k_sage<<<gGemm, 256, 0, stream>>>(mean, xb, WT1l, WT1r, b1, h, N);
  k_agg<<<gAggBlocks, 256, 0, stream>>>((const uint2*)h, (uint2*)mean, rowptr, sorted, N, nWaves);
  k_sage<<<gGemm, 256, 0, stream>>>(mean, h, WT2l, WT2r, b2, h, N);
  k_dec<<<gGemm, 256, 0, stream>>>(h, WTd, bd, x, alp, (float*)d_out, N);
}